// Round 1
// baseline (900.152 us; speedup 1.0000x reference)
//
#include <hip/hip_runtime.h>

// Problem constants (match reference setup_inputs).
#define D_C 128
#define EPS 1e-6f

// Build per-clause and per-variable (folded literal) linked lists over edges.
// head1[clause] -> first edge, next1[e] -> next edge with same clause.
// head2[var]    -> first edge, next2[e] -> next edge touching this var (either literal).
__global__ void build_lists_kernel(const int* __restrict__ rows,
                                   const int* __restrict__ cols,
                                   int* __restrict__ head1, int* __restrict__ next1,
                                   int* __restrict__ head2, int* __restrict__ next2,
                                   int nnz, int n_vars) {
    int e = blockIdx.x * blockDim.x + threadIdx.x;
    if (e >= nnz) return;
    int r = rows[e];
    next1[e] = atomicExch(&head1[r], e);
    int c = cols[e];
    int v = (c >= n_vars) ? (c - n_vars) : c;
    next2[e] = atomicExch(&head2[v], e);
}

// One wave (64 lanes) per variable. Each lane owns 2 of the 128 dims (float2).
// For each edge of this variable, recompute the owning clause's value vector
// (sum over that clause's edges of val * variables[col % n_vars]) plus its
// degree column, accumulate back with this edge's val, then mean-subtract and
// RMS-normalize.
__global__ void __launch_bounds__(256)
fused_compute_kernel(const float* __restrict__ vars,
                     const float* __restrict__ vals,
                     const int* __restrict__ rows,
                     const int* __restrict__ cols,
                     const int* __restrict__ head1, const int* __restrict__ next1,
                     const int* __restrict__ head2, const int* __restrict__ next2,
                     float* __restrict__ out,
                     int n_vars) {
    int wave = (blockIdx.x * blockDim.x + threadIdx.x) >> 6;
    int lane = threadIdx.x & 63;
    if (wave >= n_vars) return;

    float accx = 0.0f, accy = 0.0f;   // var_new (this lane's 2 dims)
    float degacc = 0.0f;              // var_new_deg[:, 128] (the "+1" column)

    for (int e2 = head2[wave]; e2 >= 0; e2 = next2[e2]) {
        float val2 = vals[e2];
        int r = rows[e2];
        float csx = 0.0f, csy = 0.0f; // clause value, this lane's 2 dims
        float cdeg = 0.0f;            // clause degree column
        for (int e1 = head1[r]; e1 >= 0; e1 = next1[e1]) {
            float val1 = vals[e1];
            int c1 = cols[e1];
            int v1 = (c1 >= n_vars) ? (c1 - n_vars) : c1;
            const float2 x = *(const float2*)(vars + (size_t)v1 * D_C + lane * 2);
            csx = fmaf(val1, x.x, csx);
            csy = fmaf(val1, x.y, csy);
            cdeg += val1;
        }
        accx = fmaf(val2, csx, accx);
        accy = fmaf(val2, csy, accy);
        degacc = fmaf(val2, cdeg, degacc);
    }

    float inv = 1.0f / fmaxf(degacc, 2.0f);
    const float2 mv = *(const float2*)(vars + (size_t)wave * D_C + lane * 2);
    float vx = mv.x - accx * inv;
    float vy = mv.y - accy * inv;

    float ss = vx * vx + vy * vy;
    #pragma unroll
    for (int off = 32; off > 0; off >>= 1)
        ss += __shfl_xor(ss, off, 64);
    float variance = ss * (1.0f / (float)D_C);
    float scale = rsqrtf(variance + EPS);

    float2 o;
    o.x = vx * scale;
    o.y = vy * scale;
    *(float2*)(out + (size_t)wave * D_C + lane * 2) = o;
}

extern "C" void kernel_launch(void* const* d_in, const int* in_sizes, int n_in,
                              void* d_out, int out_size, void* d_ws, size_t ws_size,
                              hipStream_t stream) {
    const float* vars = (const float*)d_in[0];
    const float* vals = (const float*)d_in[1];
    const int*   rows = (const int*)d_in[2];
    const int*   cols = (const int*)d_in[3];
    float* out = (float*)d_out;

    const int nnz    = in_sizes[1];
    const int n_vars = in_sizes[0] / D_C;
    const int n_clauses = 400000;  // adj_rows range per reference

    // Workspace layout (ints): head1[n_clauses] | head2[n_vars] | next1[nnz] | next2[nnz]
    int* head1 = (int*)d_ws;
    int* head2 = head1 + n_clauses;
    int* next1 = head2 + n_vars;
    int* next2 = next1 + nnz;

    // heads = -1 (0xFF bytes); next arrays don't need init.
    hipMemsetAsync(head1, 0xFF, (size_t)(n_clauses + n_vars) * sizeof(int), stream);

    int bthreads = 256;
    int bblocks = (nnz + bthreads - 1) / bthreads;
    build_lists_kernel<<<bblocks, bthreads, 0, stream>>>(rows, cols, head1, next1,
                                                         head2, next2, nnz, n_vars);

    int cthreads = 256;                       // 4 waves per block
    int cblocks = (n_vars * 64 + cthreads - 1) / cthreads;
    fused_compute_kernel<<<cblocks, cthreads, 0, stream>>>(vars, vals, rows, cols,
                                                           head1, next1, head2, next2,
                                                           out, n_vars);
}